// Round 1
// baseline (164.164 us; speedup 1.0000x reference)
//
#include <hip/hip_runtime.h>
#include <hip/hip_bf16.h>
#include <math.h>

// Problem constants (fixed by setup_inputs)
#define BB 32
#define LL 128
#define DD 300
#define PD 50
#define KW 12          // window K
#define NP 3044        // number of (emo,cau) pairs for L=128, K=12
#define FF 650         // 2*D + pos_dim
#define NR 25          // 2K+1 distinct relative positions
#define LN_EPS 1e-5f

// ---------------------------------------------------------------------------
// misc1: block 0 writes the (emo, cau) pair index lists;
//        blocks 1..5 compute smooth[r][k] = sum_d cnt[d]*exp(-(r-d)^2)*pos_emb[d][k]
// ---------------------------------------------------------------------------
__device__ __forceinline__ int row_start(int i) {
    // pairs before emo-row i (L=128, K=12)
    if (i <= 12) return i * 13 + (i * (i - 1)) / 2;
    if (i <= 116) return 222 + 25 * (i - 12);
    int s = i - 116;
    return 2822 + 24 * s - (s * (s - 1)) / 2;
}

__global__ __launch_bounds__(256) void misc1_kernel(
    const float* __restrict__ pos_emb,   // [25,50]
    int* __restrict__ emo, int* __restrict__ cau,
    float* __restrict__ smooth)          // [25,50]
{
    int tid = threadIdx.x;
    if (blockIdx.x == 0) {
        // pair lists: one thread per emo row i
        if (tid < LL) {
            int i = tid;
            int lo = i - KW; if (lo < 0) lo = 0;
            int hi = i + KW; if (hi > LL - 1) hi = LL - 1;
            int s = row_start(i);
            for (int j = lo; j <= hi; j++) {
                emo[s] = i;
                cau[s] = j;
                s++;
            }
        }
    } else {
        int idx = (blockIdx.x - 1) * 256 + tid;   // 0 .. 1249
        if (idx < NR * PD) {
            int r = idx / PD;
            int k = idx - r * PD;
            float acc = 0.f;
            #pragma unroll
            for (int d = 0; d < NR; d++) {
                int ad = d - KW; if (ad < 0) ad = -ad;
                float cnt = (float)(LL - ad);
                float diff = (float)(r - d);
                acc += cnt * expf(-diff * diff) * pos_emb[d * PD + k];
            }
            smooth[idx] = acc;
        }
    }
}

// ---------------------------------------------------------------------------
// misc2: P[r][dd] = b_hid[dd] + sum_k smooth[r][k] * W_hid[dd][600+k]
// ---------------------------------------------------------------------------
__global__ __launch_bounds__(256) void misc2_kernel(
    const float* __restrict__ smooth, const float* __restrict__ W_hid,
    const float* __restrict__ b_hid, float* __restrict__ P)
{
    int idx = blockIdx.x * 256 + threadIdx.x;   // 0 .. 7499
    if (idx >= NR * DD) return;
    int r = idx / DD;
    int dd = idx - r * DD;
    float acc = b_hid[dd];
    const float* w = W_hid + dd * FF + 2 * DD;
    const float* s = smooth + r * PD;
    #pragma unroll
    for (int k = 0; k < PD; k++) acc += s[k] * w[k];
    P[idx] = acc;
}

// ---------------------------------------------------------------------------
// gemm: E[bl][d] = sum_k (h_e[bl][k]+h_share[bl][k]) * W_hid[d][k]        (z=0)
//       C[bl][d] = sum_k (h_c[bl][k]+h_share[bl][k]) * W_hid[d][300+k]    (z=1)
// 64x64 tiles, K-chunks of 16, 4x4 micro-tile per thread, float4 LDS reads
// ---------------------------------------------------------------------------
#define TM 64
#define TN 64
#define TKC 16

__global__ __launch_bounds__(256) void gemm_kernel(
    const float* __restrict__ h_e, const float* __restrict__ h_c,
    const float* __restrict__ h_share, const float* __restrict__ W_hid,
    float* __restrict__ E, float* __restrict__ Cc)
{
    __shared__ float As[TKC][TM + 4];   // +4 pad keeps rows 16B-aligned, breaks conflicts
    __shared__ float Ws[TKC][TN + 4];

    const int which = blockIdx.z;
    const float* A = which ? h_c : h_e;
    float* O = which ? Cc : E;
    const int woff = which * DD;

    const int row0 = blockIdx.x * TM;   // bl tile
    const int col0 = blockIdx.y * TN;   // d tile
    const int tid = threadIdx.x;
    const int tx = tid & 15;
    const int ty = tid >> 4;

    float acc[4][4] = {};

    for (int k0 = 0; k0 < DD; k0 += TKC) {
        // cooperative load: 1024 elems each of A-tile and W-tile, 4 per thread
        #pragma unroll
        for (int q = 0; q < 4; q++) {
            int lin = tid + 256 * q;
            int m = lin >> 4;
            int kk = lin & 15;
            int k = k0 + kk;
            float va = 0.f, vw = 0.f;
            if (k < DD) {
                int bl = row0 + m;                       // always < 4096
                va = A[bl * DD + k] + h_share[bl * DD + k];
                int d = col0 + m;
                if (d < DD) vw = W_hid[d * FF + woff + k];
            }
            As[kk][m] = va;
            Ws[kk][m] = vw;
        }
        __syncthreads();

        #pragma unroll
        for (int kk = 0; kk < TKC; kk++) {
            float4 a4 = *(const float4*)&As[kk][ty * 4];
            float4 b4 = *(const float4*)&Ws[kk][tx * 4];
            float a[4] = {a4.x, a4.y, a4.z, a4.w};
            float b[4] = {b4.x, b4.y, b4.z, b4.w};
            #pragma unroll
            for (int u = 0; u < 4; u++)
                #pragma unroll
                for (int v = 0; v < 4; v++)
                    acc[u][v] += a[u] * b[v];
        }
        __syncthreads();
    }

    #pragma unroll
    for (int u = 0; u < 4; u++) {
        int bl = row0 + ty * 4 + u;
        #pragma unroll
        for (int v = 0; v < 4; v++) {
            int d = col0 + tx * 4 + v;
            if (d < DD) O[bl * DD + d] = acc[u][v];
        }
    }
}

// ---------------------------------------------------------------------------
// pair kernel: one wave per (b, pair). h = E[b,emo] + C[b,cau] + P[rel];
// LayerNorm over 300, ELU, dot with W_rel, + b_rel.
// ---------------------------------------------------------------------------
__global__ __launch_bounds__(256) void pair_kernel(
    const float* __restrict__ E, const float* __restrict__ Cc,
    const float* __restrict__ P, const int* __restrict__ emo,
    const int* __restrict__ cau, const float* __restrict__ ln_g,
    const float* __restrict__ ln_b, const float* __restrict__ W_rel,
    const float* __restrict__ b_rel, float* __restrict__ out)
{
    const int wid = threadIdx.x >> 6;
    const int lane = threadIdx.x & 63;
    const int slot = blockIdx.x * 4 + wid;      // grid sized exactly: no bound check needed
    const int b = slot / NP;
    const int p = slot - b * NP;

    const int i = emo[p];
    const int j = cau[p];
    const float* e = E + (b * LL + i) * DD;
    const float* c = Cc + (b * LL + j) * DD;
    const float* pr = P + (j - i + KW) * DD;

    float h[5];
    float s = 0.f;
    #pragma unroll
    for (int t = 0; t < 5; t++) {
        int d = lane + 64 * t;
        h[t] = 0.f;
        if (d < DD) {
            h[t] = e[d] + c[d] + pr[d];
            s += h[t];
        }
    }
    #pragma unroll
    for (int m = 1; m < 64; m <<= 1) s += __shfl_xor(s, m, 64);
    const float mean = s * (1.f / (float)DD);

    float vs = 0.f;
    #pragma unroll
    for (int t = 0; t < 5; t++) {
        int d = lane + 64 * t;
        if (d < DD) {
            float df = h[t] - mean;
            vs += df * df;
        }
    }
    #pragma unroll
    for (int m = 1; m < 64; m <<= 1) vs += __shfl_xor(vs, m, 64);
    const float rstd = rsqrtf(vs * (1.f / (float)DD) + LN_EPS);

    float acc = 0.f;
    #pragma unroll
    for (int t = 0; t < 5; t++) {
        int d = lane + 64 * t;
        if (d < DD) {
            float y = (h[t] - mean) * rstd * ln_g[d] + ln_b[d];
            float el = y > 0.f ? y : (__expf(y) - 1.f);
            acc += el * W_rel[d];
        }
    }
    #pragma unroll
    for (int m = 1; m < 64; m <<= 1) acc += __shfl_xor(acc, m, 64);

    if (lane == 0) out[slot] = acc + b_rel[0];
}

// ---------------------------------------------------------------------------
extern "C" void kernel_launch(void* const* d_in, const int* in_sizes, int n_in,
                              void* d_out, int out_size, void* d_ws, size_t ws_size,
                              hipStream_t stream) {
    const float* h_e     = (const float*)d_in[0];
    const float* h_c     = (const float*)d_in[1];
    const float* h_share = (const float*)d_in[2];
    const float* pos_emb = (const float*)d_in[3];
    const float* W_hid   = (const float*)d_in[4];
    const float* b_hid   = (const float*)d_in[5];
    const float* ln_g    = (const float*)d_in[6];
    const float* ln_b    = (const float*)d_in[7];
    const float* W_rel   = (const float*)d_in[8];
    const float* b_rel   = (const float*)d_in[9];
    // d_in[10] is K = 12 (hard-coded via setup shapes)

    float* out = (float*)d_out;

    // workspace layout
    float* ws = (float*)d_ws;
    float* E      = ws;                          // 32*128*300 = 1228800
    float* C      = E + BB * LL * DD;            // 1228800
    float* P      = C + BB * LL * DD;            // 25*300 = 7500
    float* smooth = P + NR * DD;                 // 25*50 = 1250
    int*   emo    = (int*)(smooth + NR * PD);    // 3044
    int*   cau    = emo + NP;                    // 3044

    // 1) pair index lists + smooth position embeddings
    misc1_kernel<<<dim3(6), dim3(256), 0, stream>>>(pos_emb, emo, cau, smooth);

    // 2) P = smooth @ W3^T + b_hid  (25 x 300)
    misc2_kernel<<<dim3(30), dim3(256), 0, stream>>>(smooth, W_hid, b_hid, P);

    // 3) E and C GEMMs (z = 0 -> E, z = 1 -> C)
    gemm_kernel<<<dim3((BB * LL) / TM, (DD + TN - 1) / TN, 2), dim3(256), 0, stream>>>(
        h_e, h_c, h_share, W_hid, E, C);

    // 4) per-pair LN + ELU + dot
    pair_kernel<<<dim3((BB * NP) / 4), dim3(256), 0, stream>>>(
        E, C, P, emo, cau, ln_g, ln_b, W_rel, b_rel, out);
}

// Round 2
// 144.219 us; speedup vs baseline: 1.1383x; 1.1383x over previous
//
#include <hip/hip_runtime.h>
#include <hip/hip_bf16.h>
#include <math.h>

// Problem constants (fixed by setup_inputs)
#define BB 32
#define LL 128
#define DD 300
#define PD 50
#define KW 12          // window K
#define NP 3044        // number of (emo,cau) pairs for L=128, K=12
#define FF 650         // 2*D + pos_dim
#define NR 25          // 2K+1 distinct relative positions
#define KP 320         // K padded for MFMA (10 x 32)
#define NPAD 320       // N padded
#define MM 4096        // B*L
#define LN_EPS 1e-5f

typedef __attribute__((ext_vector_type(8))) short short8;
typedef __attribute__((ext_vector_type(4))) float f32x4;
typedef __attribute__((ext_vector_type(4))) unsigned short us4;
typedef __attribute__((ext_vector_type(4))) int i32x4;

__device__ __forceinline__ unsigned short f2b(float f) {
    union { float f; unsigned int u; } v; v.f = f;
    unsigned int u = v.u;
    unsigned int r = u + 0x7FFFu + ((u >> 16) & 1u);   // RNE
    return (unsigned short)(r >> 16);
}

__device__ __forceinline__ int row_start(int i) {
    // pairs before emo-row i (L=128, K=12)
    if (i <= 12) return i * 13 + (i * (i - 1)) / 2;
    if (i <= 116) return 222 + 25 * (i - 12);
    int s = i - 116;
    return 2822 + 24 * s - (s * (s - 1)) / 2;
}

// ---------------------------------------------------------------------------
// misc: block r (25 blocks): smooth[r][:] in LDS, then P[r][dd]
//   smooth[r][k] = sum_d (128-|d-12|) * exp(-(r-d)^2) * pos_emb[d][k]
//   P[r][dd]     = b_hid[dd] + sum_k smooth[r][k] * W_hid[dd][600+k]
// ---------------------------------------------------------------------------
__global__ __launch_bounds__(256) void misc_kernel(
    const float* __restrict__ pos_emb, const float* __restrict__ W_hid,
    const float* __restrict__ b_hid, float* __restrict__ P)
{
    __shared__ float sm[PD];
    const int r = blockIdx.x;
    const int tid = threadIdx.x;
    if (tid < PD) {
        float acc = 0.f;
        #pragma unroll
        for (int d = 0; d < NR; d++) {
            int ad = d - KW; if (ad < 0) ad = -ad;
            float cnt = (float)(LL - ad);
            float diff = (float)(r - d);
            acc += cnt * expf(-diff * diff) * pos_emb[d * PD + tid];
        }
        sm[tid] = acc;
    }
    __syncthreads();
    for (int dd = tid; dd < DD; dd += 256) {
        float a = b_hid[dd];
        const float* w = W_hid + dd * FF + 2 * DD;
        #pragma unroll
        for (int k = 0; k < PD; k++) a += sm[k] * w[k];
        P[r * DD + dd] = a;
    }
}

// ---------------------------------------------------------------------------
// conv: build bf16 operands
//   Abf[z][m][kp]  (z=0: h_e+h_share, z=1: h_c+h_share), kp>=300 -> 0
//   Wbf[z][d][kp]  = W_hid[d][z*300+kp]  (d<300,kp<300) else 0   ([n][k] layout)
// ---------------------------------------------------------------------------
#define CONV_A_BLOCKS 2560   // 2*4096*80 threads, 4 k's each
#define CONV_W_BLOCKS 800    // 2*320*320 threads, 1 elem each

__global__ __launch_bounds__(256) void conv_kernel(
    const float* __restrict__ h_e, const float* __restrict__ h_c,
    const float* __restrict__ h_share, const float* __restrict__ W_hid,
    unsigned short* __restrict__ Abf, unsigned short* __restrict__ Wbf)
{
    if (blockIdx.x < CONV_A_BLOCKS) {
        int idx = blockIdx.x * 256 + threadIdx.x;      // 0 .. 655359
        int z = idx / (MM * 80);
        int rem = idx - z * (MM * 80);
        int m = rem / 80;
        int kg = rem - m * 80;
        int k = kg * 4;
        us4 o;
        if (k < DD) {
            const float* A = z ? h_c : h_e;
            const float4 a = *(const float4*)&A[m * DD + k];
            const float4 s = *(const float4*)&h_share[m * DD + k];
            o.x = f2b(a.x + s.x); o.y = f2b(a.y + s.y);
            o.z = f2b(a.z + s.z); o.w = f2b(a.w + s.w);
        } else {
            o.x = 0; o.y = 0; o.z = 0; o.w = 0;
        }
        *(us4*)&Abf[(z * MM + m) * KP + k] = o;
    } else {
        int idx = (blockIdx.x - CONV_A_BLOCKS) * 256 + threadIdx.x;  // 0 .. 204799
        int z = idx / (NPAD * KP);
        int rem = idx - z * (NPAD * KP);
        int d = rem / KP;
        int k = rem - d * KP;
        unsigned short v = 0;
        if (d < DD && k < DD) v = f2b(W_hid[d * FF + z * DD + k]);
        Wbf[idx] = v;
    }
}

// ---------------------------------------------------------------------------
// MFMA GEMM: O[z][m][d] = sum_k Abf[z][m][k] * Wbf[z][d][k]
// block: 256 threads (4 waves). M-tile 64 (16 rows/wave), N-tile 160, K loop 320.
// B tile staged in LDS (padded rows: 40 bf16 -> 2-way banks = free).
// ---------------------------------------------------------------------------
__global__ __launch_bounds__(256) void gemm_kernel(
    const unsigned short* __restrict__ Abf, const unsigned short* __restrict__ Wbf,
    float* __restrict__ E, float* __restrict__ Cc)
{
    __shared__ unsigned short Bs[160 * 40];

    const int z = blockIdx.z;
    const int m0 = blockIdx.x * 64;
    const int n0 = blockIdx.y * 160;
    const int tid = threadIdx.x;
    const int wid = tid >> 6;
    const int lane = tid & 63;
    const int nn = lane & 15;          // frag row/col within 16
    const int q  = lane >> 4;          // k-chunk quad

    const unsigned short* Arow = Abf + (size_t)(z * MM + m0 + wid * 16 + nn) * KP + q * 8;
    const unsigned short* Wbase = Wbf + (size_t)(z * NPAD + n0) * KP;

    f32x4 acc[10];
    #pragma unroll
    for (int f = 0; f < 10; f++) acc[f] = (f32x4){0.f, 0.f, 0.f, 0.f};

    for (int k0 = 0; k0 < KP; k0 += 32) {
        // stage B chunk: 160 rows x 32 k (64B/row) -> LDS, 16B per transfer
        for (int i = tid; i < 640; i += 256) {
            int n = i >> 2;
            int c = i & 3;
            i32x4 v = *(const i32x4*)&Wbase[n * KP + k0 + c * 8];
            *(i32x4*)&Bs[n * 40 + c * 8] = v;
        }
        __syncthreads();

        short8 a = *(const short8*)&Arow[k0];
        #pragma unroll
        for (int f = 0; f < 10; f++) {
            short8 b = *(const short8*)&Bs[(f * 16 + nn) * 40 + q * 8];
            acc[f] = __builtin_amdgcn_mfma_f32_16x16x32_bf16(a, b, acc[f], 0, 0, 0);
        }
        __syncthreads();
    }

    float* O = z ? Cc : E;
    const int row = m0 + wid * 16 + q * 4;     // C/D: row = (lane>>4)*4 + reg
    #pragma unroll
    for (int f = 0; f < 10; f++) {
        int col = n0 + f * 16 + nn;            // C/D: col = lane&15
        if (col < DD) {
            #pragma unroll
            for (int r = 0; r < 4; r++)
                O[(size_t)(row + r) * DD + col] = acc[f][r];
        }
    }
}

// ---------------------------------------------------------------------------
// pair kernel: one wave per (b, i). E row + ln params register-cached;
// loop j in [i-K, i+K] ∩ [0,128): h = e + C[b,j] + P[j-i+K]; LN; ELU; dot W_rel.
// ---------------------------------------------------------------------------
__global__ __launch_bounds__(256) void pair_kernel(
    const float* __restrict__ E, const float* __restrict__ Cc,
    const float* __restrict__ P, const float* __restrict__ ln_g,
    const float* __restrict__ ln_b, const float* __restrict__ W_rel,
    const float* __restrict__ b_rel, float* __restrict__ out)
{
    const int wid = threadIdx.x >> 6;
    const int lane = threadIdx.x & 63;
    const int slot = blockIdx.x * 4 + wid;     // 0 .. 4095 exact
    const int b = slot >> 7;
    const int i = slot & 127;

    const float* e_row = E + (size_t)(b * LL + i) * DD;

    float e[5], g[5], gb[5], wr[5];
    #pragma unroll
    for (int t = 0; t < 5; t++) {
        int d = lane + 64 * t;
        if (d < DD) {
            e[t]  = e_row[d];
            g[t]  = ln_g[d];
            gb[t] = ln_b[d];
            wr[t] = W_rel[d];
        } else {
            e[t] = 0.f; g[t] = 0.f; gb[t] = 0.f; wr[t] = 0.f;
        }
    }
    const float brel = b_rel[0];

    int jlo = i - KW; if (jlo < 0) jlo = 0;
    int jhi = i + KW; if (jhi > LL - 1) jhi = LL - 1;
    int p = b * NP + row_start(i);

    for (int j = jlo; j <= jhi; j++, p++) {
        const float* c_row = Cc + (size_t)(b * LL + j) * DD;
        const float* p_row = P + (j - i + KW) * DD;

        float h[5];
        float s = 0.f, ss = 0.f;
        #pragma unroll
        for (int t = 0; t < 5; t++) {
            int d = lane + 64 * t;
            h[t] = 0.f;
            if (d < DD) {
                h[t] = e[t] + c_row[d] + p_row[d];
                s += h[t];
                ss += h[t] * h[t];
            }
        }
        #pragma unroll
        for (int m = 1; m < 64; m <<= 1) {
            s  += __shfl_xor(s, m, 64);
            ss += __shfl_xor(ss, m, 64);
        }
        const float mean = s * (1.f / (float)DD);
        const float var = ss * (1.f / (float)DD) - mean * mean;
        const float rstd = rsqrtf(var + LN_EPS);

        float acc = 0.f;
        #pragma unroll
        for (int t = 0; t < 5; t++) {
            int d = lane + 64 * t;
            if (d < DD) {
                float y = (h[t] - mean) * rstd * g[t] + gb[t];
                float el = y > 0.f ? y : (__expf(y) - 1.f);
                acc += el * wr[t];
            }
        }
        #pragma unroll
        for (int m = 1; m < 64; m <<= 1) acc += __shfl_xor(acc, m, 64);

        if (lane == 0) out[p] = acc + brel;
    }
}

// ---------------------------------------------------------------------------
extern "C" void kernel_launch(void* const* d_in, const int* in_sizes, int n_in,
                              void* d_out, int out_size, void* d_ws, size_t ws_size,
                              hipStream_t stream) {
    const float* h_e     = (const float*)d_in[0];
    const float* h_c     = (const float*)d_in[1];
    const float* h_share = (const float*)d_in[2];
    const float* pos_emb = (const float*)d_in[3];
    const float* W_hid   = (const float*)d_in[4];
    const float* b_hid   = (const float*)d_in[5];
    const float* ln_g    = (const float*)d_in[6];
    const float* ln_b    = (const float*)d_in[7];
    const float* W_rel   = (const float*)d_in[8];
    const float* b_rel   = (const float*)d_in[9];

    float* out = (float*)d_out;

    // workspace layout
    float* ws = (float*)d_ws;
    float* E   = ws;                             // 4096*300 = 1228800 f32
    float* C   = E + (size_t)MM * DD;            // 1228800 f32
    float* P   = C + (size_t)MM * DD;            // 25*300 f32
    unsigned short* Abf = (unsigned short*)(P + NR * DD);   // 2*4096*320 u16
    unsigned short* Wbf = Abf + (size_t)2 * MM * KP;        // 2*320*320 u16

    // 1) P = (Gaussian-smoothed counts @ pos_emb) @ W3^T + b_hid
    misc_kernel<<<dim3(NR), dim3(256), 0, stream>>>(pos_emb, W_hid, b_hid, P);

    // 2) fp32 -> bf16 operand build
    conv_kernel<<<dim3(CONV_A_BLOCKS + CONV_W_BLOCKS), dim3(256), 0, stream>>>(
        h_e, h_c, h_share, W_hid, Abf, Wbf);

    // 3) MFMA GEMMs: E and C
    gemm_kernel<<<dim3(MM / 64, 2, 2), dim3(256), 0, stream>>>(Abf, Wbf, E, C);

    // 4) per-(b,i) LN + ELU + dot over the j-window
    pair_kernel<<<dim3(BB * LL / 4), dim3(256), 0, stream>>>(
        E, C, P, ln_g, ln_b, W_rel, b_rel, out);
}

// Round 3
// 131.416 us; speedup vs baseline: 1.2492x; 1.0974x over previous
//
#include <hip/hip_runtime.h>
#include <hip/hip_bf16.h>
#include <math.h>

// Problem constants (fixed by setup_inputs)
#define BB 32
#define LL 128
#define DD 300
#define PD 50
#define KW 12          // window K
#define NP 3044        // number of (emo,cau) pairs for L=128, K=12
#define FF 650         // 2*D + pos_dim
#define NR 25          // 2K+1 distinct relative positions
#define KP 320         // K padded for MFMA (10 x 32)
#define NPAD 320       // N padded
#define MM 4096        // B*L
#define LN_EPS 1e-5f

typedef __attribute__((ext_vector_type(8))) short short8;
typedef __attribute__((ext_vector_type(4))) float f32x4;
typedef __attribute__((ext_vector_type(4))) int i32x4;

__device__ __forceinline__ unsigned short f2b(float f) {
    union { float f; unsigned int u; } v; v.f = f;
    unsigned int u = v.u;
    unsigned int r = u + 0x7FFFu + ((u >> 16) & 1u);   // RNE
    return (unsigned short)(r >> 16);
}

__device__ __forceinline__ int row_start(int i) {
    // pairs before emo-row i (L=128, K=12)
    if (i <= 12) return i * 13 + (i * (i - 1)) / 2;
    if (i <= 116) return 222 + 25 * (i - 12);
    int s = i - 116;
    return 2822 + 24 * s - (s * (s - 1)) / 2;
}

// ---------------------------------------------------------------------------
// prep: blocks 0..24      -> P[r][dd] (Gaussian-smoothed pos emb through W3)
//       blocks 25..824    -> Wbf[z][d][k] bf16 ([n][k] layout, zero padded)
// ---------------------------------------------------------------------------
#define PREP_W_BLOCKS 800    // 2*320*320 / 256

__global__ __launch_bounds__(256) void prep_kernel(
    const float* __restrict__ pos_emb, const float* __restrict__ W_hid,
    const float* __restrict__ b_hid, float* __restrict__ P,
    unsigned short* __restrict__ Wbf)
{
    const int tid = threadIdx.x;
    if (blockIdx.x < NR) {
        __shared__ float sm[PD];
        const int r = blockIdx.x;
        if (tid < PD) {
            float acc = 0.f;
            #pragma unroll
            for (int d = 0; d < NR; d++) {
                int ad = d - KW; if (ad < 0) ad = -ad;
                float cnt = (float)(LL - ad);
                float diff = (float)(r - d);
                acc += cnt * expf(-diff * diff) * pos_emb[d * PD + tid];
            }
            sm[tid] = acc;
        }
        __syncthreads();
        for (int dd = tid; dd < DD; dd += 256) {
            float a = b_hid[dd];
            const float* w = W_hid + dd * FF + 2 * DD;
            #pragma unroll
            for (int k = 0; k < PD; k++) a += sm[k] * w[k];
            P[r * DD + dd] = a;
        }
    } else {
        int idx = (blockIdx.x - NR) * 256 + tid;     // 0 .. 204799
        int z = idx / (NPAD * KP);
        int rem = idx - z * (NPAD * KP);
        int d = rem / KP;
        int k = rem - d * KP;
        unsigned short v = 0;
        if (d < DD && k < DD) v = f2b(W_hid[d * FF + z * DD + k]);
        Wbf[idx] = v;
    }
}

// ---------------------------------------------------------------------------
// MFMA GEMM: O[z][m][d] = sum_k bf16(h_x[m][k]+h_share[m][k]) * Wbf[z][d][k]
// A fragment built in-register from fp32 (no staging pass). B tile in LDS.
// block: 256 threads (4 waves). M-tile 64, N-tile 160, K = 320 (300 + pad).
// ---------------------------------------------------------------------------
__global__ __launch_bounds__(256) void gemm_kernel(
    const float* __restrict__ h_e, const float* __restrict__ h_c,
    const float* __restrict__ h_share, const unsigned short* __restrict__ Wbf,
    float* __restrict__ E, float* __restrict__ Cc)
{
    __shared__ unsigned short Bs[160 * 40];

    const int z = blockIdx.z;
    const int m0 = blockIdx.x * 64;
    const int n0 = blockIdx.y * 160;
    const int tid = threadIdx.x;
    const int wid = tid >> 6;
    const int lane = tid & 63;
    const int nn = lane & 15;          // frag m / n within 16
    const int q  = lane >> 4;          // k-chunk quad

    const int row = m0 + wid * 16 + nn;
    const float* xr = (z ? h_c : h_e) + (size_t)row * DD;
    const float* sr = h_share + (size_t)row * DD;
    const unsigned short* Wbase = Wbf + (size_t)(z * NPAD + n0) * KP;

    f32x4 acc[10];
    #pragma unroll
    for (int f = 0; f < 10; f++) acc[f] = (f32x4){0.f, 0.f, 0.f, 0.f};

    for (int k0 = 0; k0 < KP; k0 += 32) {
        // stage B chunk: 160 rows x 32 k (64B/row) -> LDS, 16B per transfer
        for (int i = tid; i < 640; i += 256) {
            int n = i >> 2;
            int c = i & 3;
            i32x4 v = *(const i32x4*)&Wbase[n * KP + k0 + c * 8];
            *(i32x4*)&Bs[n * 40 + c * 8] = v;
        }
        __syncthreads();

        // build A fragment: 8 k's starting at kb, fp32 add + bf16 round
        const int kb = k0 + q * 8;
        float a8[8];
        if (kb + 7 < DD) {
            float4 x0 = *(const float4*)&xr[kb];
            float4 x1 = *(const float4*)&xr[kb + 4];
            float4 s0 = *(const float4*)&sr[kb];
            float4 s1 = *(const float4*)&sr[kb + 4];
            a8[0] = x0.x + s0.x; a8[1] = x0.y + s0.y;
            a8[2] = x0.z + s0.z; a8[3] = x0.w + s0.w;
            a8[4] = x1.x + s1.x; a8[5] = x1.y + s1.y;
            a8[6] = x1.z + s1.z; a8[7] = x1.w + s1.w;
        } else {
            #pragma unroll
            for (int u = 0; u < 8; u++) {
                int k = kb + u;
                a8[u] = (k < DD) ? (xr[k] + sr[k]) : 0.f;
            }
        }
        short8 a;
        #pragma unroll
        for (int u = 0; u < 8; u++) a[u] = (short)f2b(a8[u]);

        #pragma unroll
        for (int f = 0; f < 10; f++) {
            short8 b = *(const short8*)&Bs[(f * 16 + nn) * 40 + q * 8];
            acc[f] = __builtin_amdgcn_mfma_f32_16x16x32_bf16(a, b, acc[f], 0, 0, 0);
        }
        __syncthreads();
    }

    float* O = z ? Cc : E;
    const int orow = m0 + wid * 16 + q * 4;    // C/D: row = (lane>>4)*4 + reg
    #pragma unroll
    for (int f = 0; f < 10; f++) {
        int col = n0 + f * 16 + nn;            // C/D: col = lane&15
        if (col < DD) {
            #pragma unroll
            for (int r = 0; r < 4; r++)
                O[(size_t)(orow + r) * DD + col] = acc[f][r];
        }
    }
}

// ---------------------------------------------------------------------------
// pair kernel: block per (b, i); 4 waves split the j-window (j = jlo+wid+4t).
// E row + ln params register-cached per wave; fused sum/sumsq single pass.
// ---------------------------------------------------------------------------
__global__ __launch_bounds__(256) void pair_kernel(
    const float* __restrict__ E, const float* __restrict__ Cc,
    const float* __restrict__ P, const float* __restrict__ ln_g,
    const float* __restrict__ ln_b, const float* __restrict__ W_rel,
    const float* __restrict__ b_rel, float* __restrict__ out)
{
    const int wid = threadIdx.x >> 6;
    const int lane = threadIdx.x & 63;
    const int slot = blockIdx.x;               // 0 .. 4095
    const int b = slot >> 7;
    const int i = slot & 127;

    const float* e_row = E + (size_t)(b * LL + i) * DD;

    float e[5], g[5], gb[5], wr[5];
    #pragma unroll
    for (int t = 0; t < 5; t++) {
        int d = lane + 64 * t;
        if (d < DD) {
            e[t]  = e_row[d];
            g[t]  = ln_g[d];
            gb[t] = ln_b[d];
            wr[t] = W_rel[d];
        } else {
            e[t] = 0.f; g[t] = 0.f; gb[t] = 0.f; wr[t] = 0.f;
        }
    }
    const float brel = b_rel[0];

    int jlo = i - KW; if (jlo < 0) jlo = 0;
    int jhi = i + KW; if (jhi > LL - 1) jhi = LL - 1;
    const int base = b * NP + row_start(i);

    for (int j = jlo + wid; j <= jhi; j += 4) {
        const float* c_row = Cc + (size_t)(b * LL + j) * DD;
        const float* p_row = P + (j - i + KW) * DD;

        float h[5];
        float s = 0.f, ss = 0.f;
        #pragma unroll
        for (int t = 0; t < 5; t++) {
            int d = lane + 64 * t;
            h[t] = 0.f;
            if (d < DD) {
                h[t] = e[t] + c_row[d] + p_row[d];
                s += h[t];
                ss += h[t] * h[t];
            }
        }
        #pragma unroll
        for (int m = 1; m < 64; m <<= 1) {
            s  += __shfl_xor(s, m, 64);
            ss += __shfl_xor(ss, m, 64);
        }
        const float mean = s * (1.f / (float)DD);
        float var = ss * (1.f / (float)DD) - mean * mean;
        if (var < 0.f) var = 0.f;
        const float rstd = rsqrtf(var + LN_EPS);

        float acc = 0.f;
        #pragma unroll
        for (int t = 0; t < 5; t++) {
            int d = lane + 64 * t;
            if (d < DD) {
                float y = (h[t] - mean) * rstd * g[t] + gb[t];
                float el = y > 0.f ? y : (__expf(y) - 1.f);
                acc += el * wr[t];
            }
        }
        #pragma unroll
        for (int m = 1; m < 64; m <<= 1) acc += __shfl_xor(acc, m, 64);

        if (lane == 0) out[base + (j - jlo)] = acc + brel;
    }
}

// ---------------------------------------------------------------------------
extern "C" void kernel_launch(void* const* d_in, const int* in_sizes, int n_in,
                              void* d_out, int out_size, void* d_ws, size_t ws_size,
                              hipStream_t stream) {
    const float* h_e     = (const float*)d_in[0];
    const float* h_c     = (const float*)d_in[1];
    const float* h_share = (const float*)d_in[2];
    const float* pos_emb = (const float*)d_in[3];
    const float* W_hid   = (const float*)d_in[4];
    const float* b_hid   = (const float*)d_in[5];
    const float* ln_g    = (const float*)d_in[6];
    const float* ln_b    = (const float*)d_in[7];
    const float* W_rel   = (const float*)d_in[8];
    const float* b_rel   = (const float*)d_in[9];

    float* out = (float*)d_out;

    // workspace layout
    float* ws = (float*)d_ws;
    float* E   = ws;                             // 4096*300 f32
    float* C   = E + (size_t)MM * DD;            // 4096*300 f32
    float* P   = C + (size_t)MM * DD;            // 25*300 f32
    unsigned short* Wbf = (unsigned short*)(P + NR * DD);   // 2*320*320 u16

    // 1) P rows + bf16 weight operand
    prep_kernel<<<dim3(NR + PREP_W_BLOCKS), dim3(256), 0, stream>>>(
        pos_emb, W_hid, b_hid, P, Wbf);

    // 2) MFMA GEMMs with in-register A conversion: E and C
    gemm_kernel<<<dim3(MM / 64, 2, 2), dim3(256), 0, stream>>>(
        h_e, h_c, h_share, Wbf, E, C);

    // 3) per-(b,i) block, 4 waves over the j-window: LN + ELU + dot
    pair_kernel<<<dim3(BB * LL), dim3(256), 0, stream>>>(
        E, C, P, ln_g, ln_b, W_rel, b_rel, out);
}